// Round 3
// baseline (144.589 us; speedup 1.0000x reference)
//
#include <hip/hip_runtime.h>
#include <stdint.h>

#pragma clang fp contract(off)

#define N_ANCH 90000
#define M_TOP  1024          // selection scope; walk fast path covers M_L=512
#define M_L    512           // mask/walk fast-path scope; stop row ~330 for this input
#define NW_L   8             // mask words per row (M_L/64)
#define K_POST 300
#define CAP    2048          // candidate capacity (power of 2 for bitonic)
#define WINB   0x3D00        // hist window base: p>=~0.031, covers ~99.3% of valid keys
#define WINSZ  768           // window bins [0x3D00, 0x4000) — all bins >= WINB
#define MIN_SIZE (16.0f / 800.0f)
#define IOU_THR  0.7f

#define NB_D   176           // decode blocks (x512 thr; 1 anchor/thread; 176*512=90112)
#define NB_S   16            // sortmask blocks (each builds a 256-word mask slice)
#define G4     (N_ANCH / 4)  // 22500 uint4 key groups

// sb[] bank-conflict swizzle: +1 float4 per 64 rows -> broadcast groups hit distinct banks
#define SIDX(j) ((j) + ((j) >> 6))
#define SB_SZ   (M_L + NW_L)

// ---- workspace layout (bytes); NO aliasing (intra-kernel cross-block hazards) ----
// every region is written before it is read; no memset needed
#define OFF_CNT   0                          // 64 B   (plain store by sortmask blk 0)
#define OFF_HIST  64                         // u16[768*176] = 270336 -> 270400
#define OFF_ROI   270400                     // float4[90000] = 1440000 -> 1710400
#define OFF_KEYS  1710400                    // u32[90000] = 360000 -> 2070400
#define OFF_MASK  2070400                    // u64[4096] = 32768 -> 2103168
#define OFF_SBOX  2103168                    // float4[1024] = 16384 -> 2119552

// ============================================================================
// 1) decode: 176 blocks x 512, one anchor/thread. Writes roi, keys, and the
//    TRANSPOSED u16 hist hist[bin*176 + bid] (per-bin row = 352 contiguous
//    bytes = 22 uint4) so sortmask's per-bin sum is fully vectorized.
// ============================================================================
__global__ void __launch_bounds__(512)
decode_kernel(const float2* __restrict__ cls,
              const float4* __restrict__ reg,
              const float4* __restrict__ anc,
              float4* __restrict__ roi,
              unsigned* __restrict__ keys,
              unsigned short* __restrict__ hist) {
    __shared__ int lh[WINSZ];
    const int tid = threadIdx.x;
    const int bid = blockIdx.x;
    for (int k = tid; k < WINSZ; k += 512) lh[k] = 0;
    __syncthreads();

    const int n = bid * 512 + tid;
    if (n < N_ANCH) {
        float4 a = anc[n];
        float4 r = reg[n];
        float aw  = a.z - a.x;
        float ah  = a.w - a.y;
        float acx = (a.z + a.x) * 0.5f;
        float acy = (a.w + a.y) * 0.5f;
        float cx = r.x * aw + acx;
        float cy = r.y * ah + acy;
        float w  = expf(r.z) * aw;
        float h  = expf(r.w) * ah;
        float x1 = fminf(fmaxf(cx - w * 0.5f, 0.0f), 1.0f);
        float y1 = fminf(fmaxf(cy - h * 0.5f, 0.0f), 1.0f);
        float x2 = fminf(fmaxf(cx + w * 0.5f, 0.0f), 1.0f);
        float y2 = fminf(fmaxf(cy + h * 0.5f, 0.0f), 1.0f);
        roi[n] = make_float4(x1, y1, x2, y2);

        float2 c = cls[n];
        float m  = fmaxf(c.x, c.y);
        float e0 = expf(c.x - m);
        float e1 = expf(c.y - m);
        float p  = e1 / (e0 + e1);

        bool ok = ((x2 - x1) >= MIN_SIZE) && ((y2 - y1) >= MIN_SIZE);
        unsigned key = ok ? (__float_as_uint(p) ^ 0x80000000u) : 0u;  // monotone; invalid -> 0
        keys[n] = key;
        if (key != 0u) {
            int hb = (int)(key >> 16) - 0x8000;
            if (hb >= WINB) atomicAdd(&lh[hb - WINB], 1);
            // p<1 => hb <= 0x3F7F < WINB+WINSZ: window covers all bins >= WINB
        }
    }
    __syncthreads();
    for (int k = tid; k < WINSZ; k += 512)
        hist[k * NB_D + bid] = (unsigned short)lh[k];   // count <= 512 fits u16
}

// ============================================================================
// 2) sortmask: 16 blocks x 1024. EACH block redundantly (deterministically
//    identical across blocks):
//      a) threshold from transposed hist (sum + reversed scan)
//      b) compact all 90000 keys into LDS via block-wide prefix (NO atomics ->
//         identical order and identical overflow-drops in every block)
//      c) bitonic-sort the 2048-slot array descending (u64 = key<<32 | ~idx;
//         unique -> ties impossible; key desc, idx asc == reference top_k order)
//      d) gather roi for rows 0..511 into swizzled sb
//    then builds ITS 256-word mask slice (threads 0..255).
//    Block 0 additionally publishes sbox[0..1023] and cnt[0] for the walk.
// ============================================================================
__global__ void __launch_bounds__(1024)
sortmask_kernel(const unsigned* __restrict__ keys,
                const unsigned short* __restrict__ hist,
                const float4* __restrict__ roi,
                float4* __restrict__ sbox,
                int* __restrict__ cnt,
                unsigned long long* __restrict__ mask) {
    __shared__ int rscan[1024];
    __shared__ unsigned s_thr;
    __shared__ unsigned long long sc[CAP];   // 16 KB candidate/sort buffer
    __shared__ float4 sb[SB_SZ];             // 8.3 KB mask boxes
    const int t = threadIdx.x;
    const int bid = blockIdx.x;

    // ---- a) threshold: per-bin total over 176 decode blocks (22 uint4 each) ----
    int wsum = 0;
    if (t < WINSZ) {
        const int bin = WINSZ - 1 - t;       // reversed: rscan[t] = #keys in bins >= bin
        const uint4* hp = (const uint4*)(hist + bin * NB_D);
#pragma unroll
        for (int q = 0; q < NB_D / 8; ++q) { // 22
            uint4 v = hp[q];
            wsum += (int)((v.x & 0xffffu) + (v.x >> 16) + (v.y & 0xffffu) + (v.y >> 16)
                        + (v.z & 0xffffu) + (v.z >> 16) + (v.w & 0xffffu) + (v.w >> 16));
        }
    }
    rscan[t] = wsum;
    __syncthreads();
    for (int off = 1; off < 1024; off <<= 1) {
        int add = (t >= off) ? rscan[t - off] : 0;
        __syncthreads();
        rscan[t] += add;
        __syncthreads();
    }
    if (t < WINSZ && rscan[t] >= M_TOP && (t == 0 || rscan[t - 1] < M_TOP))
        s_thr = ((unsigned)(0x8000 + WINB + (WINSZ - 1 - t))) << 16;
    if (t == 0 && rscan[WINSZ - 1] < M_TOP)
        s_thr = 0x80000000u;                 // window insufficient: take all valid keys
    __syncthreads();
    const unsigned thr = s_thr;

    // ---- b) deterministic compact: count -> block scan -> append ----
    const uint4* k4 = (const uint4*)keys;
    int mycnt = 0;
#pragma unroll
    for (int q = 0; q < 22; ++q) {
        int g = q * 1024 + t;
        if (g < G4) {
            uint4 kv = k4[g];
            mycnt += (kv.x >= thr) + (kv.y >= thr) + (kv.z >= thr) + (kv.w >= thr);
        }
    }
    __syncthreads();                         // rscan reads above are complete
    rscan[t] = mycnt;
    __syncthreads();
    for (int off = 1; off < 1024; off <<= 1) {
        int add = (t >= off) ? rscan[t - off] : 0;
        __syncthreads();
        rscan[t] += add;
        __syncthreads();
    }
    int base = rscan[t] - mycnt;             // exclusive prefix (order: by t, then q, then lane)
    const int ctot = rscan[1023];
    const int c = (ctot < CAP) ? ctot : CAP;
#pragma unroll
    for (int q = 0; q < 22; ++q) {
        int g = q * 1024 + t;
        if (g < G4) {
            uint4 kv = k4[g];                // L1/L2-hot reload
            int n0 = g * 4;
            if (kv.x >= thr) { if (base < CAP) sc[base] = ((unsigned long long)kv.x << 32) | (unsigned)(~(unsigned)n0);       ++base; }
            if (kv.y >= thr) { if (base < CAP) sc[base] = ((unsigned long long)kv.y << 32) | (unsigned)(~(unsigned)(n0 + 1)); ++base; }
            if (kv.z >= thr) { if (base < CAP) sc[base] = ((unsigned long long)kv.z << 32) | (unsigned)(~(unsigned)(n0 + 2)); ++base; }
            if (kv.w >= thr) { if (base < CAP) sc[base] = ((unsigned long long)kv.w << 32) | (unsigned)(~(unsigned)(n0 + 3)); ++base; }
        }
    }
    for (int k = t; k < CAP; k += 1024)
        if (k >= c) sc[k] = 0ULL;            // pad sinks to the bottom in desc sort
    __syncthreads();

    // ---- c) bitonic sort descending, 1024 threads = 1 pair each, 66 stages ----
    for (int kk = 2; kk <= CAP; kk <<= 1) {
        for (int j = kk >> 1; j > 0; j >>= 1) {
            int e = ((t & ~(j - 1)) << 1) | (t & (j - 1));
            int p = e | j;
            unsigned long long a = sc[e], b = sc[p];
            bool desc = ((e & kk) == 0);
            if (desc ? (a < b) : (a > b)) { sc[e] = b; sc[p] = a; }
            __syncthreads();
        }
    }

    // ---- d) gather boxes; block 0 publishes sbox + cnt ----
    if (t < M_L) {
        unsigned long long v = sc[t];
        float4 bx = (t < c) ? roi[~(unsigned)v] : make_float4(0.f, 0.f, 0.f, 0.f);
        sb[SIDX(t)] = bx;
        if (bid == 0) sbox[t] = bx;
    } else if (bid == 0) {                   // t in [512, 1024)
        unsigned long long v = sc[t];
        sbox[t] = (t < c) ? roi[~(unsigned)v] : make_float4(0.f, 0.f, 0.f, 0.f);
    }
    if (bid == 0 && t == 0) cnt[0] = c;
    __syncthreads();

    // ---- mask slice: threads 0..255, 1 word (64 IoUs) each ----
    if (t < 256) {
        int wid = bid * 256 + t;             // [0, 4096)
        int i = wid >> 3;
        int w = wid & 7;
        unsigned long long bits = 0;
        int j0 = w << 6;
        if (j0 + 63 > i) {                   // skip words fully below diagonal
            float4 bi = sb[SIDX(i)];
            float ai = (bi.z - bi.x) * (bi.w - bi.y);
            for (int b = 0; b < 64; ++b) {
                int j = j0 + b;
                if (j > i) {
                    float4 bj = sb[SIDX(j)];
                    float xx1 = fmaxf(bi.x, bj.x);
                    float yy1 = fmaxf(bi.y, bj.y);
                    float xx2 = fminf(bi.z, bj.z);
                    float yy2 = fminf(bi.w, bj.w);
                    float ww = fmaxf(xx2 - xx1, 0.0f);
                    float hh = fmaxf(yy2 - yy1, 0.0f);
                    float inter = ww * hh;
                    float aj = (bj.z - bj.x) * (bj.w - bj.y);
                    float uni = ai + aj - inter;
                    float iou = inter / fmaxf(uni, 1e-12f);
                    if (iou > IOU_THR) bits |= 1ull << b;
                }
            }
        }
        mask[wid] = bits;
    }
}

__device__ __forceinline__ unsigned long long readlane64(unsigned long long v, int sl) {
    unsigned lo = (unsigned)__builtin_amdgcn_readlane((int)(unsigned)v, sl);
    unsigned hi = (unsigned)__builtin_amdgcn_readlane((int)(unsigned)(v >> 32), sl);
    return ((unsigned long long)hi << 32) | lo;
}

// ============================================================================
// 3) serial greedy walk, wave 0; full 32 KB mask preloaded into LDS by 256 thr
// ============================================================================
__global__ void __launch_bounds__(256)
walk_kernel(const unsigned long long* __restrict__ mask,
            const float4* __restrict__ sbox,
            const int* __restrict__ cnt,
            float4* __restrict__ out) {
    __shared__ unsigned long long lmask[M_L * NW_L];   // 32 KB
    __shared__ int s_keep[K_POST];
    __shared__ int s_kc;
    const int tid = threadIdx.x;

    {   // cooperative preload: 2048 uint4, 8 per thread, independent loads
        const uint4* src = (const uint4*)mask;
        uint4* dst = (uint4*)lmask;
#pragma unroll
        for (int q = 0; q < (M_L * NW_L) / 2 / 256; ++q)
            dst[tid + q * 256] = src[tid + q * 256];
    }
    __syncthreads();

    if (tid < 64) {
        int lane = tid;
        int c_eff = cnt[0];
        if (c_eff > M_TOP) c_eff = M_TOP;

        unsigned long long diag[NW_L];
#pragma unroll
        for (int cc = 0; cc < NW_L; ++cc)
            diag[cc] = lmask[(((cc << 6) | lane) << 3) + cc];

        unsigned long long remw = 0;             // every lane holds remv word (lane&7)
        int w = lane & 7;
        int kgrp = lane >> 3;
        int kc = 0;                              // uniform
        bool stop = false;
#pragma unroll
        for (int cc = 0; cc < NW_L; ++cc) {
            int base = cc << 6;
            unsigned long long valid =
                (c_eff >= base + 64) ? ~0ull
              : ((c_eff <= base) ? 0ull : ((1ull << (c_eff - base)) - 1ull));
            unsigned long long live = valid & ~readlane64(remw, cc);
            unsigned long long keptbits = 0;
            while (live) {
                int b = __ffsll((unsigned long long)live) - 1;
                keptbits |= 1ull << b;
                if (lane == 0) s_keep[kc] = base + b;
                ++kc;
                if (kc >= K_POST) { stop = true; break; }
                live &= ~readlane64(diag[cc], b);
                live &= ~(1ull << b);
            }
            if (stop) break;
            if (cc == NW_L - 1) break;
            if (keptbits) {
                int nk = __popcll(keptbits);
                // lane l computes position of l-th set bit of keptbits
                int mypos = 0;
                if (lane < nk) {
                    unsigned long long tmp = keptbits;
                    for (int p = 0; p < lane; ++p) tmp &= tmp - 1;
                    mypos = base + (__ffsll((unsigned long long)tmp) - 1);
                }
                // batched folds from LDS; OR-reduce over kept rows
                unsigned long long acc = 0;
#pragma unroll
                for (int r = 0; r < 8; ++r) {    // covers up to 64 kept rows/chunk
                    int kg = (r << 3) | kgrp;
                    int row = __shfl(mypos, kg);
                    unsigned long long v = (kg < nk) ? lmask[(row << 3) + w] : 0ull;
                    acc |= v;
                }
                acc |= __shfl_xor(acc, 8);
                acc |= __shfl_xor(acc, 16);
                acc |= __shfl_xor(acc, 32);
                remw |= acc;
            }
        }
        // cold fallback: rows [M_L, c_eff) vs kept set (correctness only)
        if (!stop) {
            for (int i = M_L; i < c_eff && kc < K_POST; ++i) {
                float4 bi = sbox[i];
                float ai = (bi.z - bi.x) * (bi.w - bi.y);
                bool any = false;
                for (int k = lane; k < kc; k += 64) {
                    float4 bk = sbox[s_keep[k]];
                    float xx1 = fmaxf(bi.x, bk.x);
                    float yy1 = fmaxf(bi.y, bk.y);
                    float xx2 = fminf(bi.z, bk.z);
                    float yy2 = fminf(bi.w, bk.w);
                    float ww = fmaxf(xx2 - xx1, 0.0f);
                    float hh = fmaxf(yy2 - yy1, 0.0f);
                    float inter = ww * hh;
                    float ak = (bk.z - bk.x) * (bk.w - bk.y);
                    float uni = ai + ak - inter;
                    if (inter / fmaxf(uni, 1e-12f) > IOU_THR) any = true;
                }
                if (__ballot(any) == 0ull) {
                    if (lane == 0) s_keep[kc] = i;
                    ++kc;
                }
            }
        }
        if (lane == 0) s_kc = kc;
    }
    __syncthreads();
    int kcf = s_kc;
    for (int j = tid; j < K_POST; j += 256)
        out[j] = (j < kcf) ? sbox[s_keep[j]] : make_float4(0.f, 0.f, 0.f, 0.f);
}

extern "C" void kernel_launch(void* const* d_in, const int* in_sizes, int n_in,
                              void* d_out, int out_size, void* d_ws, size_t ws_size,
                              hipStream_t stream) {
    const float2* cls = (const float2*)d_in[0];   // (1,100,100,18) fp32 -> logit pairs
    const float4* reg = (const float4*)d_in[1];   // (1,90000,4)
    const float4* anc = (const float4*)d_in[2];   // (90000,4)
    float4* out = (float4*)d_out;                 // 300 x 4 fp32

    char* ws = (char*)d_ws;
    int*                cnt  = (int*)(ws + OFF_CNT);
    unsigned short*     hist = (unsigned short*)(ws + OFF_HIST);
    float4*             roi  = (float4*)(ws + OFF_ROI);
    unsigned*           keys = (unsigned*)(ws + OFF_KEYS);
    unsigned long long* mask = (unsigned long long*)(ws + OFF_MASK);
    float4*             sbox = (float4*)(ws + OFF_SBOX);

    decode_kernel<<<NB_D, 512, 0, stream>>>(cls, reg, anc, roi, keys, hist);
    sortmask_kernel<<<NB_S, 1024, 0, stream>>>(keys, hist, roi, sbox, cnt, mask);
    walk_kernel<<<1, 256, 0, stream>>>(mask, sbox, cnt, out);
}